// Round 7
// baseline (620.488 us; speedup 1.0000x reference)
//
#include <hip/hip_runtime.h>

typedef float f32x2 __attribute__((ext_vector_type(2)));

#define C_ 3
#define L_ 3
#define HB 38          // staged buffer rows/cols (32 + 2*3 halo)
#define WB 43          // padded LDS row stride (odd -> bank spread)
#define BUFSZ (C_*HB*WB)
#define NT   384       // threads/block in k_main (6 waves)

// ws layout (float indices)
#define WS_LDPART 0      // 48 per-block logdet partials
#define WS_LDC2   48     // 16384 * sum(als)
#define WS_CC     64     // 9 folded bias constants
#define WS_IALPHA 80     // 9
#define WS_WD     96     // 243 duplicated weight pairs (f32x2) = 486 floats
#define WS_LDACC  2048   // B per-batch accumulators
#define WS_TAB    8192   // float2 tabp[9][128][136], x-padded (+3 wrap each side)

#define TAB_CH    17408  // 128*136 float2 per (layer,channel)
#define TAB_ROW   136

// ---------------- kernel 1: fused preprocessing ----------------------------
// blocks 0..611   : fill x-padded epilogue table (9*128*136 / 256 = 612)
// blocks 612..659 : logdet spectral partials (48, one ws slot each)
// block  660      : fold+duplicate weights, zero accumulators, constants
__global__ void k_pre(const float* __restrict__ ab,   // actnorm_bias (L,1,C,1,1)
                      const float* __restrict__ als,  // actnorm_log_scale
                      const float* __restrict__ K,    // (L,C,C,3,3)
                      const float* __restrict__ la,   // slog_log_alpha
                      const float* __restrict__ cls,  // conv_log_scale (L,1,C,N,N)
                      const float* __restrict__ cb,   // conv_bias      (L,1,C,N,N)
                      float* __restrict__ ws,
                      float2* __restrict__ tab, int B)
{
    __shared__ float sK[81];
    __shared__ float red[4];
    const int bid = blockIdx.x;
    const int t = threadIdx.x;

    if (bid < 612) {
        // tabp[ch][y][xp] = (a*exp(cls[ch][y][gx]), a*cb[ch][y][gx]), gx=(xp-3)&127
        int idx = bid*256 + t;           // < 156672
        int ch  = idx / TAB_CH;
        int rem = idx - ch*TAB_CH;
        int y   = rem / TAB_ROW;
        int xp  = rem - y*TAB_ROW;
        int gx  = (xp - 3) & 127;
        float a = __expf(la[ch]);
        int src = ch*16384 + (y << 7) + gx;
        tab[idx] = make_float2(a*__expf(cls[src]), a*cb[src]);
        return;
    }
    if (bid < 660) {
        int lb  = bid - 612;
        int li  = lb >> 4;
        int sub = lb & 15;
        if (t < 81) sK[t] = K[li*81 + t];
        __syncthreads();
        float part = 0.f;
        {   // slice of sum(cls)
            const float* p = cls + li*(3*128*128) + sub*3072;
            for (int i = t; i < 3072; i += 256) part += p[i];
        }
        const float w0 = -(2.f * 3.14159265358979f / 128.f);
        for (int f = sub*1024 + t; f < sub*1024 + 1024; f += 256) {
            int u = f >> 7, v = f & 127;
            float su, cu, sv, cv;
            __sincosf(w0 * (float)u, &su, &cu);
            __sincosf(w0 * (float)v, &sv, &cv);
            float cu2 = cu*cu - su*su, su2 = 2.f*cu*su;
            float cv2 = cv*cv - sv*sv, sv2 = 2.f*cv*sv;
            float evr[3] = {1.f, cv, cv2}, evi[3] = {0.f, sv, sv2};
            float eur[3] = {1.f, cu, cu2}, eui[3] = {0.f, su, su2};
            float Mr[3][3], Mi[3][3];
            #pragma unroll
            for (int o = 0; o < 3; ++o)
            #pragma unroll
            for (int i2 = 0; i2 < 3; ++i2) {
                float mr = 0.f, mi = 0.f;
                #pragma unroll
                for (int p = 0; p < 3; ++p) {
                    float rr = 0.f, ri = 0.f;
                    #pragma unroll
                    for (int q = 0; q < 3; ++q) {
                        float k = sK[(o*3+i2)*9 + p*3 + q];
                        rr += k * evr[q]; ri += k * evi[q];
                    }
                    mr += eur[p]*rr - eui[p]*ri;
                    mi += eur[p]*ri + eui[p]*rr;
                }
                Mr[o][i2] = mr; Mi[o][i2] = mi;
            }
            float c0r = (Mr[1][1]*Mr[2][2]-Mi[1][1]*Mi[2][2]) - (Mr[1][2]*Mr[2][1]-Mi[1][2]*Mi[2][1]);
            float c0i = (Mr[1][1]*Mi[2][2]+Mi[1][1]*Mr[2][2]) - (Mr[1][2]*Mi[2][1]+Mi[1][2]*Mr[2][1]);
            float c1r = (Mr[1][0]*Mr[2][2]-Mi[1][0]*Mi[2][2]) - (Mr[1][2]*Mr[2][0]-Mi[1][2]*Mi[2][0]);
            float c1i = (Mr[1][0]*Mi[2][2]+Mi[1][0]*Mr[2][2]) - (Mr[1][2]*Mi[2][0]+Mi[1][2]*Mr[2][0]);
            float c2r = (Mr[1][0]*Mr[2][1]-Mi[1][0]*Mi[2][1]) - (Mr[1][1]*Mr[2][0]-Mi[1][1]*Mi[2][0]);
            float c2i = (Mr[1][0]*Mi[2][1]+Mi[1][0]*Mr[2][1]) - (Mr[1][1]*Mi[2][0]+Mi[1][1]*Mr[2][0]);
            float dr = (Mr[0][0]*c0r-Mi[0][0]*c0i) - (Mr[0][1]*c1r-Mi[0][1]*c1i) + (Mr[0][2]*c2r-Mi[0][2]*c2i);
            float di = (Mr[0][0]*c0i+Mi[0][0]*c0r) - (Mr[0][1]*c1i+Mi[0][1]*c1r) + (Mr[0][2]*c2i+Mi[0][2]*c2r);
            part += 0.5f * __logf(dr*dr + di*di);
        }
        #pragma unroll
        for (int o = 32; o > 0; o >>= 1) part += __shfl_down(part, o, 64);
        if ((t & 63) == 0) red[t >> 6] = part;
        __syncthreads();
        if (t == 0) ws[WS_LDPART + lb] = red[0]+red[1]+red[2]+red[3];
        return;
    }
    // ---- init block (256 threads; all scalar work in t<10, weights t<243) ----
    for (int i = t; i < B; i += 256) ws[WS_LDACC + i] = 0.f;
    if (t < 243) {
        // wd[li][ic][dy][oc*3+dx] = (w,w), w = K[li][oc][ic][dy][dx]*exp(als[li][ic])
        int li = t / 81; int r1 = t % 81; int ic = r1 / 27; int r2 = r1 % 27;
        int dy = r2 / 9; int r3 = r2 % 9; int oc = r3 / 3; int dx = r3 % 3;
        float v = K[((li*3+oc)*3+ic)*9 + dy*3 + dx] * __expf(als[li*3 + ic]);
        ws[WS_WD + 2*t    ] = v;
        ws[WS_WD + 2*t + 1] = v;
    }
    if (t < 9) {
        int li = t / 3, oc = t % 3;
        float s = 0.f;
        for (int ic = 0; ic < 3; ++ic) {
            float ks = 0.f;
            for (int k9 = 0; k9 < 9; ++k9) ks += K[((li*3+oc)*3+ic)*9 + k9];
            s += ab[li*3 + ic] * ks;
        }
        ws[WS_CC + t] = s;
        ws[WS_IALPHA + t] = __expf(-la[t]);
    }
    if (t == 9) {
        float s9 = 0.f;
        for (int i = 0; i < 9; ++i) s9 += als[i];
        ws[WS_LDC2] = 16384.f * s9;
    }
}

// ---------------- kernel 2: fused 3-layer main pass ------------------------
template<int S, bool FINAL>
static __device__ __forceinline__ void stage_fn(
    const float* src, float* dst,
    const float* __restrict__ ws, const float2* __restrict__ tab,
    int y0, int x0, float& ldpos, float* __restrict__ outb)
{
    constexpr int LI = S - 1;
    constexpr int W  = HB - 2*S;         // valid span this stage (36,34,32)
    constexpr int QX = (W + 3) / 4;      // pixel quads per row (9,9,8)
    constexpr int Q  = W * QX;
    const f32x2* __restrict__ wd = (const f32x2*)(ws + WS_WD);
    for (int q = threadIdx.x; q < Q; q += NT) {
        int qy  = q / QX;
        int iy  = S + qy;
        int ix0 = S + 4 * (q - qy*QX);
        // ---- EARLY ISSUE of epilogue table loads (global/L2, ~200-400cy) ----
        // Addresses depend only on q; issuing them BEFORE the conv FMA chain
        // hides their latency under ~480 cycles of VALU work. Statically
        // indexed tc[][] stays in registers (rule: no runtime indexing).
        int gy = (y0 + iy - 3) & 127;
        const float2* tp0 = tab + LI*3*TAB_CH + gy*TAB_ROW + x0 + ix0;
        float2 tc[3][4];
        #pragma unroll
        for (int oc = 0; oc < 3; ++oc) {
            const float2* tp = tp0 + oc*TAB_CH;
            #pragma unroll
            for (int j = 0; j < 4; ++j) tc[oc][j] = tp[j];
        }
        // ---- conv core (horizontal pk-pair scheme, r4) ----
        f32x2 alo[3], ahi[3];
        #pragma unroll
        for (int oc = 0; oc < 3; ++oc) {
            float cc = ws[WS_CC + LI*3 + oc];
            alo[oc] = (f32x2){cc, cc};
            ahi[oc] = (f32x2){cc, cc};
        }
        #pragma unroll
        for (int ic = 0; ic < 3; ++ic) {
            #pragma unroll
            for (int dy = 0; dy < 3; ++dy) {
                const float* rp = src + (ic*HB + iy - 1 + dy)*WB + ix0 - 1;
                f32x2 p0 = {rp[0], rp[1]};
                f32x2 p1 = {rp[1], rp[2]};
                f32x2 p2 = {rp[2], rp[3]};
                f32x2 p3 = {rp[3], rp[4]};
                f32x2 p4 = {rp[4], rp[5]};
                const f32x2* wrow = wd + ((LI*3 + ic)*3 + dy)*9;
                #pragma unroll
                for (int oc = 0; oc < 3; ++oc) {
                    f32x2 w0 = wrow[oc*3+0], w1 = wrow[oc*3+1], w2 = wrow[oc*3+2];
                    alo[oc] = __builtin_elementwise_fma(w0, p0, alo[oc]);
                    ahi[oc] = __builtin_elementwise_fma(w0, p2, ahi[oc]);
                    alo[oc] = __builtin_elementwise_fma(w1, p1, alo[oc]);
                    ahi[oc] = __builtin_elementwise_fma(w1, p3, ahi[oc]);
                    alo[oc] = __builtin_elementwise_fma(w2, p2, alo[oc]);
                    ahi[oc] = __builtin_elementwise_fma(w2, p4, ahi[oc]);
                }
            }
        }
        bool rowin = (iy >= 3 && iy < 35);
        #pragma unroll
        for (int oc = 0; oc < 3; ++oc) {
            float ia = ws[WS_IALPHA + LI*3 + oc];
            float av[4] = {alo[oc].x, alo[oc].y, ahi[oc].x, ahi[oc].y};
            float hv[4];
            #pragma unroll
            for (int j = 0; j < 4; ++j) {
                float2 tcv = tc[oc][j];
                float u  = fmaf(tcv.x, av[j], tcv.y);         // = alpha * tv
                float lg = __logf(1.f + fabsf(u));            // = alpha*|h|
                hv[j] = copysignf(lg * ia, u);
                bool in = FINAL || (rowin && (unsigned)(ix0 + j - 3) < 32u);
                if (in) ldpos += lg;
            }
            if constexpr (FINAL) {
                int gyo = y0 + iy - 3, gxo = x0 + ix0 - 3;
                float4 pk;
                pk.x = hv[0]; pk.y = hv[1]; pk.z = hv[2]; pk.w = hv[3];
                *reinterpret_cast<float4*>(outb + ((oc << 14) + (gyo << 7) + gxo)) = pk;
            } else {
                float* dp = dst + (oc*HB + iy)*WB + ix0;
                dp[0] = hv[0]; dp[1] = hv[1]; dp[2] = hv[2]; dp[3] = hv[3];
            }
        }
    }
}

__global__ __launch_bounds__(NT, 6)
void k_main(const float* __restrict__ x,
            const float* __restrict__ ws,
            const float2* __restrict__ tab,
            float* ldacc,
            float* __restrict__ outh)
{
    __shared__ float Sb[2][BUFSZ];
    __shared__ float red[NT/64];
    int t = threadIdx.x;
    int b    = blockIdx.x >> 4;
    int tile = blockIdx.x & 15;
    int y0 = (tile >> 2) << 5, x0 = (tile & 3) << 5;

    // Sb[1] cols 37,38 are read by stage 2's right edge but never written by
    // stage 1 -> zero them (deterministic). 114 rows x 2.
    if (t < 228) Sb[1][(t >> 1)*WB + 37 + (t & 1)] = 0.f;

    const float* xb = x + (size_t)b * 49152;
    // interior 32x32 per channel: coalesced float4, pure shift/mask indexing
    for (int i = t; i < 768; i += NT) {             // 2 iters
        int c = i >> 8, r = i & 255, iyr = r >> 3, ixq = (r & 7) << 2;
        float4 v = *reinterpret_cast<const float4*>(xb + c*16384 + ((y0 + iyr) << 7) + x0 + ixq);
        float* dp = &Sb[0][(c*HB + iyr + 3)*WB + 3 + ixq];
        dp[0] = v.x; dp[1] = v.y; dp[2] = v.z; dp[3] = v.w;
    }
    // halo ring: 1260 wrapped elements (rows 0-2/35-37 full, cols 0-2/35-37 sides)
    for (int i = t; i < 1260; i += NT) {
        int c = i / 420; int r = i - c*420;
        int iy, ix;
        if (r < 228) { iy = r / 38; ix = r - iy*38; if (iy >= 3) iy += 32; }
        else { int s2 = r - 228; int row = s2 / 6; int k = s2 - row*6;
               iy = 3 + row; ix = (k < 3) ? k : k + 32; }
        int gy = (y0 + iy - 3) & 127, gx = (x0 + ix - 3) & 127;
        Sb[0][(c*HB + iy)*WB + ix] = xb[c*16384 + (gy << 7) + gx];
    }
    __syncthreads();
    float ldpos = 0.f;
    stage_fn<1, false>(Sb[0], Sb[1], ws, tab, y0, x0, ldpos, nullptr);
    __syncthreads();
    stage_fn<2, false>(Sb[1], Sb[0], ws, tab, y0, x0, ldpos, nullptr);
    __syncthreads();
    stage_fn<3, true >(Sb[0], nullptr, ws, tab, y0, x0, ldpos,
                       outh + (size_t)b * 49152);
    #pragma unroll
    for (int o = 32; o > 0; o >>= 1) ldpos += __shfl_down(ldpos, o, 64);
    if ((t & 63) == 0) red[t >> 6] = ldpos;
    __syncthreads();
    if (t == 0) {
        float s = 0.f;
        #pragma unroll
        for (int wv = 0; wv < NT/64; ++wv) s += red[wv];
        atomicAdd(&ldacc[b], -s);
    }
}

// ---------------- kernel 3: finalize logdet --------------------------------
__global__ void k_fin(const float* __restrict__ ws, float* __restrict__ outld, int B)
{
    int b = blockIdx.x * 256 + threadIdx.x;
    float c = ws[WS_LDC2];
    for (int i = 0; i < 48; ++i) c += ws[WS_LDPART + i];   // uniform -> scalar loads
    if (b < B) outld[b] = c + ws[WS_LDACC + b];
}

extern "C" void kernel_launch(void* const* d_in, const int* in_sizes, int n_in,
                              void* d_out, int out_size, void* d_ws, size_t ws_size,
                              hipStream_t stream)
{
    const float* x   = (const float*)d_in[0];
    const float* ab  = (const float*)d_in[1];
    const float* als = (const float*)d_in[2];
    const float* K   = (const float*)d_in[3];
    const float* cb  = (const float*)d_in[4];
    const float* cls = (const float*)d_in[5];
    const float* la  = (const float*)d_in[6];
    float* ws = (float*)d_ws;
    float* outh = (float*)d_out;                      // fp32: reference output dtype
    float2* tab = (float2*)(ws + WS_TAB);

    const int B = in_sizes[0] / 49152;                // batch from actual input size
    float* outld = outh + (size_t)B * 49152;

    k_pre <<<661,            256, 0, stream>>>(ab, als, K, la, cls, cb, ws, tab, B);
    k_main<<<B * 16,         NT,  0, stream>>>(x, ws, tab, ws + WS_LDACC, outh);
    k_fin <<<(B + 255)/256,  256, 0, stream>>>(ws, outld, B);
}

// Round 8
// 306.188 us; speedup vs baseline: 2.0265x; 2.0265x over previous
//
#include <hip/hip_runtime.h>

typedef float f32x2 __attribute__((ext_vector_type(2)));

#define C_ 3
#define L_ 3
#define HB 38          // staged buffer rows/cols (32 + 2*3 halo)
#define WB 43          // padded LDS row stride (odd -> bank spread)
#define BUFSZ (C_*HB*WB)
#define NT   384       // threads/block in k_main (6 waves)

// ws layout (float indices)
#define WS_LDPART 0      // 48 per-block logdet partials
#define WS_LDC2   48     // 16384 * sum(als)
#define WS_CC     64     // 9 folded bias constants
#define WS_IALPHA 80     // 9
#define WS_WD     96     // 243 duplicated weight pairs (f32x2) = 486 floats
#define WS_LDACC  2048   // B per-batch accumulators
#define WS_TAB    8192   // float2 tabp[9][128][136], x-padded (+3 wrap each side)

#define TAB_CH    17408  // 128*136 float2 per (layer,channel)
#define TAB_ROW   136

// ---------------- kernel 1: fused preprocessing ----------------------------
// blocks 0..611   : fill x-padded epilogue table (9*128*136 / 256 = 612)
// blocks 612..659 : logdet spectral partials (48, one ws slot each)
// block  660      : fold+duplicate weights, zero accumulators, constants
__global__ void k_pre(const float* __restrict__ ab,   // actnorm_bias (L,1,C,1,1)
                      const float* __restrict__ als,  // actnorm_log_scale
                      const float* __restrict__ K,    // (L,C,C,3,3)
                      const float* __restrict__ la,   // slog_log_alpha
                      const float* __restrict__ cls,  // conv_log_scale (L,1,C,N,N)
                      const float* __restrict__ cb,   // conv_bias      (L,1,C,N,N)
                      float* __restrict__ ws,
                      float2* __restrict__ tab, int B)
{
    __shared__ float sK[81];
    __shared__ float red[4];
    const int bid = blockIdx.x;
    const int t = threadIdx.x;

    if (bid < 612) {
        // tabp[ch][y][xp] = (a*exp(cls[ch][y][gx]), a*cb[ch][y][gx]), gx=(xp-3)&127
        int idx = bid*256 + t;           // < 156672
        int ch  = idx / TAB_CH;
        int rem = idx - ch*TAB_CH;
        int y   = rem / TAB_ROW;
        int xp  = rem - y*TAB_ROW;
        int gx  = (xp - 3) & 127;
        float a = __expf(la[ch]);
        int src = ch*16384 + (y << 7) + gx;
        tab[idx] = make_float2(a*__expf(cls[src]), a*cb[src]);
        return;
    }
    if (bid < 660) {
        int lb  = bid - 612;
        int li  = lb >> 4;
        int sub = lb & 15;
        if (t < 81) sK[t] = K[li*81 + t];
        __syncthreads();
        float part = 0.f;
        {   // slice of sum(cls)
            const float* p = cls + li*(3*128*128) + sub*3072;
            for (int i = t; i < 3072; i += 256) part += p[i];
        }
        const float w0 = -(2.f * 3.14159265358979f / 128.f);
        for (int f = sub*1024 + t; f < sub*1024 + 1024; f += 256) {
            int u = f >> 7, v = f & 127;
            float su, cu, sv, cv;
            __sincosf(w0 * (float)u, &su, &cu);
            __sincosf(w0 * (float)v, &sv, &cv);
            float cu2 = cu*cu - su*su, su2 = 2.f*cu*su;
            float cv2 = cv*cv - sv*sv, sv2 = 2.f*cv*sv;
            float evr[3] = {1.f, cv, cv2}, evi[3] = {0.f, sv, sv2};
            float eur[3] = {1.f, cu, cu2}, eui[3] = {0.f, su, su2};
            float Mr[3][3], Mi[3][3];
            #pragma unroll
            for (int o = 0; o < 3; ++o)
            #pragma unroll
            for (int i2 = 0; i2 < 3; ++i2) {
                float mr = 0.f, mi = 0.f;
                #pragma unroll
                for (int p = 0; p < 3; ++p) {
                    float rr = 0.f, ri = 0.f;
                    #pragma unroll
                    for (int q = 0; q < 3; ++q) {
                        float k = sK[(o*3+i2)*9 + p*3 + q];
                        rr += k * evr[q]; ri += k * evi[q];
                    }
                    mr += eur[p]*rr - eui[p]*ri;
                    mi += eur[p]*ri + eui[p]*rr;
                }
                Mr[o][i2] = mr; Mi[o][i2] = mi;
            }
            float c0r = (Mr[1][1]*Mr[2][2]-Mi[1][1]*Mi[2][2]) - (Mr[1][2]*Mr[2][1]-Mi[1][2]*Mi[2][1]);
            float c0i = (Mr[1][1]*Mi[2][2]+Mi[1][1]*Mr[2][2]) - (Mr[1][2]*Mi[2][1]+Mi[1][2]*Mr[2][1]);
            float c1r = (Mr[1][0]*Mr[2][2]-Mi[1][0]*Mi[2][2]) - (Mr[1][2]*Mr[2][0]-Mi[1][2]*Mi[2][0]);
            float c1i = (Mr[1][0]*Mi[2][2]+Mi[1][0]*Mr[2][2]) - (Mr[1][2]*Mi[2][0]+Mi[1][2]*Mr[2][0]);
            float c2r = (Mr[1][0]*Mr[2][1]-Mi[1][0]*Mi[2][1]) - (Mr[1][1]*Mr[2][0]-Mi[1][1]*Mi[2][0]);
            float c2i = (Mr[1][0]*Mi[2][1]+Mi[1][0]*Mr[2][1]) - (Mr[1][1]*Mi[2][0]+Mi[1][1]*Mr[2][0]);
            float dr = (Mr[0][0]*c0r-Mi[0][0]*c0i) - (Mr[0][1]*c1r-Mi[0][1]*c1i) + (Mr[0][2]*c2r-Mi[0][2]*c2i);
            float di = (Mr[0][0]*c0i+Mi[0][0]*c0r) - (Mr[0][1]*c1i+Mi[0][1]*c1r) + (Mr[0][2]*c2i+Mi[0][2]*c2r);
            part += 0.5f * __logf(dr*dr + di*di);
        }
        #pragma unroll
        for (int o = 32; o > 0; o >>= 1) part += __shfl_down(part, o, 64);
        if ((t & 63) == 0) red[t >> 6] = part;
        __syncthreads();
        if (t == 0) ws[WS_LDPART + lb] = red[0]+red[1]+red[2]+red[3];
        return;
    }
    // ---- init block (256 threads; all scalar work in t<10, weights t<243) ----
    for (int i = t; i < B; i += 256) ws[WS_LDACC + i] = 0.f;
    if (t < 243) {
        // wd[li][ic][dy][oc*3+dx] = (w,w), w = K[li][oc][ic][dy][dx]*exp(als[li][ic])
        int li = t / 81; int r1 = t % 81; int ic = r1 / 27; int r2 = r1 % 27;
        int dy = r2 / 9; int r3 = r2 % 9; int oc = r3 / 3; int dx = r3 % 3;
        float v = K[((li*3+oc)*3+ic)*9 + dy*3 + dx] * __expf(als[li*3 + ic]);
        ws[WS_WD + 2*t    ] = v;
        ws[WS_WD + 2*t + 1] = v;
    }
    if (t < 9) {
        int li = t / 3, oc = t % 3;
        float s = 0.f;
        for (int ic = 0; ic < 3; ++ic) {
            float ks = 0.f;
            for (int k9 = 0; k9 < 9; ++k9) ks += K[((li*3+oc)*3+ic)*9 + k9];
            s += ab[li*3 + ic] * ks;
        }
        ws[WS_CC + t] = s;
        ws[WS_IALPHA + t] = __expf(-la[t]);
    }
    if (t == 9) {
        float s9 = 0.f;
        for (int i = 0; i < 9; ++i) s9 += als[i];
        ws[WS_LDC2] = 16384.f * s9;
    }
}

// ---------------- kernel 2: fused 3-layer main pass ------------------------
template<int S, bool FINAL>
static __device__ __forceinline__ void stage_fn(
    const float* src, float* dst,
    const float* __restrict__ ws, const float2* __restrict__ tab,
    int y0, int x0, float& ldpos, float* __restrict__ outb)
{
    constexpr int LI = S - 1;
    constexpr int W  = HB - 2*S;         // valid span this stage (36,34,32)
    constexpr int QX = (W + 3) / 4;      // pixel quads per row (9,9,8)
    constexpr int Q  = W * QX;
    const f32x2* __restrict__ wd = (const f32x2*)(ws + WS_WD);
    for (int q = threadIdx.x; q < Q; q += NT) {
        int qy  = q / QX;
        int iy  = S + qy;
        int ix0 = S + 4 * (q - qy*QX);
        // ---- EARLY ISSUE of epilogue table loads (global/L2, ~200-400cy). ----
        // 12 individually NAMED float2 scalars (never an array: this compiler
        // demotes small aggregate arrays to scratch even with static indexing
        // -- rounds 3 & 7 both regressed 3-5x from exactly that). Loads issued
        // before the conv FMA chain so their latency hides under ~480cy VALU.
        int gy = (y0 + iy - 3) & 127;
        const float2* tp0 = tab + LI*3*TAB_CH + gy*TAB_ROW + x0 + ix0;
        const float2* tp1 = tp0 + TAB_CH;
        const float2* tp2 = tp0 + 2*TAB_CH;
        float2 tA0 = tp0[0], tA1 = tp0[1], tA2 = tp0[2], tA3 = tp0[3];
        float2 tB0 = tp1[0], tB1 = tp1[1], tB2 = tp1[2], tB3 = tp1[3];
        float2 tC0 = tp2[0], tC1 = tp2[1], tC2 = tp2[2], tC3 = tp2[3];
        // ---- conv core (horizontal pk-pair scheme, r4) ----
        f32x2 alo[3], ahi[3];
        #pragma unroll
        for (int oc = 0; oc < 3; ++oc) {
            float cc = ws[WS_CC + LI*3 + oc];
            alo[oc] = (f32x2){cc, cc};
            ahi[oc] = (f32x2){cc, cc};
        }
        #pragma unroll
        for (int ic = 0; ic < 3; ++ic) {
            #pragma unroll
            for (int dy = 0; dy < 3; ++dy) {
                const float* rp = src + (ic*HB + iy - 1 + dy)*WB + ix0 - 1;
                f32x2 p0 = {rp[0], rp[1]};
                f32x2 p1 = {rp[1], rp[2]};
                f32x2 p2 = {rp[2], rp[3]};
                f32x2 p3 = {rp[3], rp[4]};
                f32x2 p4 = {rp[4], rp[5]};
                const f32x2* wrow = wd + ((LI*3 + ic)*3 + dy)*9;
                #pragma unroll
                for (int oc = 0; oc < 3; ++oc) {
                    f32x2 w0 = wrow[oc*3+0], w1 = wrow[oc*3+1], w2 = wrow[oc*3+2];
                    alo[oc] = __builtin_elementwise_fma(w0, p0, alo[oc]);
                    ahi[oc] = __builtin_elementwise_fma(w0, p2, ahi[oc]);
                    alo[oc] = __builtin_elementwise_fma(w1, p1, alo[oc]);
                    ahi[oc] = __builtin_elementwise_fma(w1, p3, ahi[oc]);
                    alo[oc] = __builtin_elementwise_fma(w2, p2, alo[oc]);
                    ahi[oc] = __builtin_elementwise_fma(w2, p4, ahi[oc]);
                }
            }
        }
        bool rowin = (iy >= 3 && iy < 35);
        // ---- epilogue: macro-unrolled per oc, consuming the named scalars ----
#define EPI(OC, T0, T1, T2, T3) do {                                          \
            float ia = ws[WS_IALPHA + LI*3 + (OC)];                           \
            float av0 = alo[OC].x, av1 = alo[OC].y;                           \
            float av2 = ahi[OC].x, av3 = ahi[OC].y;                           \
            float u0 = fmaf(T0.x, av0, T0.y);                                 \
            float u1 = fmaf(T1.x, av1, T1.y);                                 \
            float u2 = fmaf(T2.x, av2, T2.y);                                 \
            float u3 = fmaf(T3.x, av3, T3.y);                                 \
            float lg0 = __logf(1.f + fabsf(u0));                              \
            float lg1 = __logf(1.f + fabsf(u1));                              \
            float lg2 = __logf(1.f + fabsf(u2));                              \
            float lg3 = __logf(1.f + fabsf(u3));                              \
            float hv0 = copysignf(lg0 * ia, u0);                              \
            float hv1 = copysignf(lg1 * ia, u1);                              \
            float hv2 = copysignf(lg2 * ia, u2);                              \
            float hv3 = copysignf(lg3 * ia, u3);                              \
            if (FINAL || (rowin && (unsigned)(ix0 + 0 - 3) < 32u)) ldpos += lg0; \
            if (FINAL || (rowin && (unsigned)(ix0 + 1 - 3) < 32u)) ldpos += lg1; \
            if (FINAL || (rowin && (unsigned)(ix0 + 2 - 3) < 32u)) ldpos += lg2; \
            if (FINAL || (rowin && (unsigned)(ix0 + 3 - 3) < 32u)) ldpos += lg3; \
            if constexpr (FINAL) {                                            \
                int gyo = y0 + iy - 3, gxo = x0 + ix0 - 3;                    \
                float4 pk;                                                    \
                pk.x = hv0; pk.y = hv1; pk.z = hv2; pk.w = hv3;               \
                *reinterpret_cast<float4*>(outb + (((OC) << 14) + (gyo << 7) + gxo)) = pk; \
            } else {                                                          \
                float* dp = dst + ((OC)*HB + iy)*WB + ix0;                    \
                dp[0] = hv0; dp[1] = hv1; dp[2] = hv2; dp[3] = hv3;           \
            }                                                                 \
        } while (0)
        EPI(0, tA0, tA1, tA2, tA3);
        EPI(1, tB0, tB1, tB2, tB3);
        EPI(2, tC0, tC1, tC2, tC3);
#undef EPI
    }
}

__global__ __launch_bounds__(NT, 6)
void k_main(const float* __restrict__ x,
            const float* __restrict__ ws,
            const float2* __restrict__ tab,
            float* ldacc,
            float* __restrict__ outh)
{
    __shared__ float Sb[2][BUFSZ];
    __shared__ float red[NT/64];
    int t = threadIdx.x;
    int b    = blockIdx.x >> 4;
    int tile = blockIdx.x & 15;
    int y0 = (tile >> 2) << 5, x0 = (tile & 3) << 5;

    // Sb[1] cols 37,38 are read by stage 2's right edge but never written by
    // stage 1 -> zero them (deterministic). 114 rows x 2.
    if (t < 228) Sb[1][(t >> 1)*WB + 37 + (t & 1)] = 0.f;

    const float* xb = x + (size_t)b * 49152;
    // interior 32x32 per channel: coalesced float4, pure shift/mask indexing
    for (int i = t; i < 768; i += NT) {             // 2 iters
        int c = i >> 8, r = i & 255, iyr = r >> 3, ixq = (r & 7) << 2;
        float4 v = *reinterpret_cast<const float4*>(xb + c*16384 + ((y0 + iyr) << 7) + x0 + ixq);
        float* dp = &Sb[0][(c*HB + iyr + 3)*WB + 3 + ixq];
        dp[0] = v.x; dp[1] = v.y; dp[2] = v.z; dp[3] = v.w;
    }
    // halo ring: 1260 wrapped elements (rows 0-2/35-37 full, cols 0-2/35-37 sides)
    for (int i = t; i < 1260; i += NT) {
        int c = i / 420; int r = i - c*420;
        int iy, ix;
        if (r < 228) { iy = r / 38; ix = r - iy*38; if (iy >= 3) iy += 32; }
        else { int s2 = r - 228; int row = s2 / 6; int k = s2 - row*6;
               iy = 3 + row; ix = (k < 3) ? k : k + 32; }
        int gy = (y0 + iy - 3) & 127, gx = (x0 + ix - 3) & 127;
        Sb[0][(c*HB + iy)*WB + ix] = xb[c*16384 + (gy << 7) + gx];
    }
    __syncthreads();
    float ldpos = 0.f;
    stage_fn<1, false>(Sb[0], Sb[1], ws, tab, y0, x0, ldpos, nullptr);
    __syncthreads();
    stage_fn<2, false>(Sb[1], Sb[0], ws, tab, y0, x0, ldpos, nullptr);
    __syncthreads();
    stage_fn<3, true >(Sb[0], nullptr, ws, tab, y0, x0, ldpos,
                       outh + (size_t)b * 49152);
    #pragma unroll
    for (int o = 32; o > 0; o >>= 1) ldpos += __shfl_down(ldpos, o, 64);
    if ((t & 63) == 0) red[t >> 6] = ldpos;
    __syncthreads();
    if (t == 0) {
        float s = 0.f;
        #pragma unroll
        for (int wv = 0; wv < NT/64; ++wv) s += red[wv];
        atomicAdd(&ldacc[b], -s);
    }
}

// ---------------- kernel 3: finalize logdet --------------------------------
__global__ void k_fin(const float* __restrict__ ws, float* __restrict__ outld, int B)
{
    int b = blockIdx.x * 256 + threadIdx.x;
    float c = ws[WS_LDC2];
    for (int i = 0; i < 48; ++i) c += ws[WS_LDPART + i];   // uniform -> scalar loads
    if (b < B) outld[b] = c + ws[WS_LDACC + b];
}

extern "C" void kernel_launch(void* const* d_in, const int* in_sizes, int n_in,
                              void* d_out, int out_size, void* d_ws, size_t ws_size,
                              hipStream_t stream)
{
    const float* x   = (const float*)d_in[0];
    const float* ab  = (const float*)d_in[1];
    const float* als = (const float*)d_in[2];
    const float* K   = (const float*)d_in[3];
    const float* cb  = (const float*)d_in[4];
    const float* cls = (const float*)d_in[5];
    const float* la  = (const float*)d_in[6];
    float* ws = (float*)d_ws;
    float* outh = (float*)d_out;                      // fp32: reference output dtype
    float2* tab = (float2*)(ws + WS_TAB);

    const int B = in_sizes[0] / 49152;                // batch from actual input size
    float* outld = outh + (size_t)B * 49152;

    k_pre <<<661,            256, 0, stream>>>(ab, als, K, la, cls, cb, ws, tab, B);
    k_main<<<B * 16,         NT,  0, stream>>>(x, ws, tab, ws + WS_LDACC, outh);
    k_fin <<<(B + 255)/256,  256, 0, stream>>>(ws, outld, B);
}

// Round 9
// 283.348 us; speedup vs baseline: 2.1898x; 1.0806x over previous
//
#include <hip/hip_runtime.h>

typedef float f32x2 __attribute__((ext_vector_type(2)));

#define C_ 3
#define L_ 3
#define HB 38          // staged buffer rows/cols (32 + 2*3 halo)
#define WB 43          // padded LDS row stride (odd -> bank spread)
#define BUFSZ (C_*HB*WB)
#define NT   512       // threads/block in k_main (8 waves -> 32 waves/CU at 4 blocks)

// ws layout (float indices)
#define WS_LDPART 0      // 48 per-block logdet partials
#define WS_LDC2   48     // 16384 * sum(als)
#define WS_CC     64     // 9 folded bias constants
#define WS_IALPHA 80     // 9
#define WS_WD     96     // 243 duplicated weight pairs (f32x2) = 486 floats
#define WS_LDACC  2048   // B per-batch accumulators
#define WS_TAB    8192   // float2 tabp[9][128][136], x-padded (+3 wrap each side)

#define TAB_CH    17408  // 128*136 float2 per (layer,channel)
#define TAB_ROW   136

// ---------------- kernel 1: fused preprocessing ----------------------------
// blocks 0..611   : fill x-padded epilogue table (9*128*136 / 256 = 612)
// blocks 612..659 : logdet spectral partials (48, one ws slot each)
// block  660      : fold+duplicate weights, zero accumulators, constants
__global__ void k_pre(const float* __restrict__ ab,   // actnorm_bias (L,1,C,1,1)
                      const float* __restrict__ als,  // actnorm_log_scale
                      const float* __restrict__ K,    // (L,C,C,3,3)
                      const float* __restrict__ la,   // slog_log_alpha
                      const float* __restrict__ cls,  // conv_log_scale (L,1,C,N,N)
                      const float* __restrict__ cb,   // conv_bias      (L,1,C,N,N)
                      float* __restrict__ ws,
                      float2* __restrict__ tab, int B)
{
    __shared__ float sK[81];
    __shared__ float red[4];
    const int bid = blockIdx.x;
    const int t = threadIdx.x;

    if (bid < 612) {
        // tabp[ch][y][xp] = (a*exp(cls[ch][y][gx]), a*cb[ch][y][gx]), gx=(xp-3)&127
        int idx = bid*256 + t;           // < 156672
        int ch  = idx / TAB_CH;
        int rem = idx - ch*TAB_CH;
        int y   = rem / TAB_ROW;
        int xp  = rem - y*TAB_ROW;
        int gx  = (xp - 3) & 127;
        float a = __expf(la[ch]);
        int src = ch*16384 + (y << 7) + gx;
        tab[idx] = make_float2(a*__expf(cls[src]), a*cb[src]);
        return;
    }
    if (bid < 660) {
        int lb  = bid - 612;
        int li  = lb >> 4;
        int sub = lb & 15;
        if (t < 81) sK[t] = K[li*81 + t];
        __syncthreads();
        float part = 0.f;
        {   // slice of sum(cls)
            const float* p = cls + li*(3*128*128) + sub*3072;
            for (int i = t; i < 3072; i += 256) part += p[i];
        }
        const float w0 = -(2.f * 3.14159265358979f / 128.f);
        for (int f = sub*1024 + t; f < sub*1024 + 1024; f += 256) {
            int u = f >> 7, v = f & 127;
            float su, cu, sv, cv;
            __sincosf(w0 * (float)u, &su, &cu);
            __sincosf(w0 * (float)v, &sv, &cv);
            float cu2 = cu*cu - su*su, su2 = 2.f*cu*su;
            float cv2 = cv*cv - sv*sv, sv2 = 2.f*cv*sv;
            float evr[3] = {1.f, cv, cv2}, evi[3] = {0.f, sv, sv2};
            float eur[3] = {1.f, cu, cu2}, eui[3] = {0.f, su, su2};
            float Mr[3][3], Mi[3][3];
            #pragma unroll
            for (int o = 0; o < 3; ++o)
            #pragma unroll
            for (int i2 = 0; i2 < 3; ++i2) {
                float mr = 0.f, mi = 0.f;
                #pragma unroll
                for (int p = 0; p < 3; ++p) {
                    float rr = 0.f, ri = 0.f;
                    #pragma unroll
                    for (int q = 0; q < 3; ++q) {
                        float k = sK[(o*3+i2)*9 + p*3 + q];
                        rr += k * evr[q]; ri += k * evi[q];
                    }
                    mr += eur[p]*rr - eui[p]*ri;
                    mi += eur[p]*ri + eui[p]*rr;
                }
                Mr[o][i2] = mr; Mi[o][i2] = mi;
            }
            float c0r = (Mr[1][1]*Mr[2][2]-Mi[1][1]*Mi[2][2]) - (Mr[1][2]*Mr[2][1]-Mi[1][2]*Mi[2][1]);
            float c0i = (Mr[1][1]*Mi[2][2]+Mi[1][1]*Mr[2][2]) - (Mr[1][2]*Mi[2][1]+Mi[1][2]*Mr[2][1]);
            float c1r = (Mr[1][0]*Mr[2][2]-Mi[1][0]*Mi[2][2]) - (Mr[1][2]*Mr[2][0]-Mi[1][2]*Mi[2][0]);
            float c1i = (Mr[1][0]*Mi[2][2]+Mi[1][0]*Mr[2][2]) - (Mr[1][2]*Mi[2][0]+Mi[1][2]*Mr[2][0]);
            float c2r = (Mr[1][0]*Mr[2][1]-Mi[1][0]*Mi[2][1]) - (Mr[1][1]*Mr[2][0]-Mi[1][1]*Mi[2][0]);
            float c2i = (Mr[1][0]*Mi[2][1]+Mi[1][0]*Mr[2][1]) - (Mr[1][1]*Mi[2][0]+Mi[1][1]*Mr[2][0]);
            float dr = (Mr[0][0]*c0r-Mi[0][0]*c0i) - (Mr[0][1]*c1r-Mi[0][1]*c1i) + (Mr[0][2]*c2r-Mi[0][2]*c2i);
            float di = (Mr[0][0]*c0i+Mi[0][0]*c0r) - (Mr[0][1]*c1i+Mi[0][1]*c1r) + (Mr[0][2]*c2i+Mi[0][2]*c2r);
            part += 0.5f * __logf(dr*dr + di*di);
        }
        #pragma unroll
        for (int o = 32; o > 0; o >>= 1) part += __shfl_down(part, o, 64);
        if ((t & 63) == 0) red[t >> 6] = part;
        __syncthreads();
        if (t == 0) ws[WS_LDPART + lb] = red[0]+red[1]+red[2]+red[3];
        return;
    }
    // ---- init block (256 threads; all scalar work in t<10, weights t<243) ----
    for (int i = t; i < B; i += 256) ws[WS_LDACC + i] = 0.f;
    if (t < 243) {
        // wd[li][ic][dy][oc*3+dx] = (w,w), w = K[li][oc][ic][dy][dx]*exp(als[li][ic])
        int li = t / 81; int r1 = t % 81; int ic = r1 / 27; int r2 = r1 % 27;
        int dy = r2 / 9; int r3 = r2 % 9; int oc = r3 / 3; int dx = r3 % 3;
        float v = K[((li*3+oc)*3+ic)*9 + dy*3 + dx] * __expf(als[li*3 + ic]);
        ws[WS_WD + 2*t    ] = v;
        ws[WS_WD + 2*t + 1] = v;
    }
    if (t < 9) {
        int li = t / 3, oc = t % 3;
        float s = 0.f;
        for (int ic = 0; ic < 3; ++ic) {
            float ks = 0.f;
            for (int k9 = 0; k9 < 9; ++k9) ks += K[((li*3+oc)*3+ic)*9 + k9];
            s += ab[li*3 + ic] * ks;
        }
        ws[WS_CC + t] = s;
        ws[WS_IALPHA + t] = __expf(-la[t]);
    }
    if (t == 9) {
        float s9 = 0.f;
        for (int i = 0; i < 9; ++i) s9 += als[i];
        ws[WS_LDC2] = 16384.f * s9;
    }
}

// ---------------- kernel 2: fused 3-layer main pass ------------------------
template<int S, bool FINAL>
static __device__ __forceinline__ void stage_fn(
    const float* src, float* dst,
    const float* __restrict__ ws, const float2* __restrict__ tab,
    int y0, int x0, float& ldpos, float* __restrict__ outb)
{
    constexpr int LI = S - 1;
    constexpr int W  = HB - 2*S;         // valid span this stage (36,34,32)
    constexpr int QX = (W + 3) / 4;      // pixel quads per row (9,9,8)
    constexpr int Q  = W * QX;
    const f32x2* __restrict__ wd = (const f32x2*)(ws + WS_WD);
    for (int q = threadIdx.x; q < Q; q += NT) {
        int qy  = q / QX;
        int iy  = S + qy;
        int ix0 = S + 4 * (q - qy*QX);
        // ---- early issue of epilogue table loads (named scalars: this
        // compiler demotes small aggregate arrays to scratch -- r3/r7) ----
        int gy = (y0 + iy - 3) & 127;
        const float2* tp0 = tab + LI*3*TAB_CH + gy*TAB_ROW + x0 + ix0;
        const float2* tp1 = tp0 + TAB_CH;
        const float2* tp2 = tp0 + 2*TAB_CH;
        float2 tA0 = tp0[0], tA1 = tp0[1], tA2 = tp0[2], tA3 = tp0[3];
        float2 tB0 = tp1[0], tB1 = tp1[1], tB2 = tp1[2], tB3 = tp1[3];
        float2 tC0 = tp2[0], tC1 = tp2[1], tC2 = tp2[2], tC3 = tp2[3];
        // ---- conv core (horizontal pk-pair scheme, r4) ----
        f32x2 alo[3], ahi[3];
        #pragma unroll
        for (int oc = 0; oc < 3; ++oc) {
            float cc = ws[WS_CC + LI*3 + oc];
            alo[oc] = (f32x2){cc, cc};
            ahi[oc] = (f32x2){cc, cc};
        }
        #pragma unroll
        for (int ic = 0; ic < 3; ++ic) {
            #pragma unroll
            for (int dy = 0; dy < 3; ++dy) {
                const float* rp = src + (ic*HB + iy - 1 + dy)*WB + ix0 - 1;
                f32x2 p0 = {rp[0], rp[1]};
                f32x2 p1 = {rp[1], rp[2]};
                f32x2 p2 = {rp[2], rp[3]};
                f32x2 p3 = {rp[3], rp[4]};
                f32x2 p4 = {rp[4], rp[5]};
                const f32x2* wrow = wd + ((LI*3 + ic)*3 + dy)*9;
                #pragma unroll
                for (int oc = 0; oc < 3; ++oc) {
                    f32x2 w0 = wrow[oc*3+0], w1 = wrow[oc*3+1], w2 = wrow[oc*3+2];
                    alo[oc] = __builtin_elementwise_fma(w0, p0, alo[oc]);
                    ahi[oc] = __builtin_elementwise_fma(w0, p2, ahi[oc]);
                    alo[oc] = __builtin_elementwise_fma(w1, p1, alo[oc]);
                    ahi[oc] = __builtin_elementwise_fma(w1, p3, ahi[oc]);
                    alo[oc] = __builtin_elementwise_fma(w2, p2, alo[oc]);
                    ahi[oc] = __builtin_elementwise_fma(w2, p4, ahi[oc]);
                }
            }
        }
        bool rowin = (iy >= 3 && iy < 35);
        // ---- epilogue: macro-unrolled per oc, consuming the named scalars ----
#define EPI(OC, T0, T1, T2, T3) do {                                          \
            float ia = ws[WS_IALPHA + LI*3 + (OC)];                           \
            float av0 = alo[OC].x, av1 = alo[OC].y;                           \
            float av2 = ahi[OC].x, av3 = ahi[OC].y;                           \
            float u0 = fmaf(T0.x, av0, T0.y);                                 \
            float u1 = fmaf(T1.x, av1, T1.y);                                 \
            float u2 = fmaf(T2.x, av2, T2.y);                                 \
            float u3 = fmaf(T3.x, av3, T3.y);                                 \
            float lg0 = __logf(1.f + fabsf(u0));                              \
            float lg1 = __logf(1.f + fabsf(u1));                              \
            float lg2 = __logf(1.f + fabsf(u2));                              \
            float lg3 = __logf(1.f + fabsf(u3));                              \
            float hv0 = copysignf(lg0 * ia, u0);                              \
            float hv1 = copysignf(lg1 * ia, u1);                              \
            float hv2 = copysignf(lg2 * ia, u2);                              \
            float hv3 = copysignf(lg3 * ia, u3);                              \
            if (FINAL || (rowin && (unsigned)(ix0 + 0 - 3) < 32u)) ldpos += lg0; \
            if (FINAL || (rowin && (unsigned)(ix0 + 1 - 3) < 32u)) ldpos += lg1; \
            if (FINAL || (rowin && (unsigned)(ix0 + 2 - 3) < 32u)) ldpos += lg2; \
            if (FINAL || (rowin && (unsigned)(ix0 + 3 - 3) < 32u)) ldpos += lg3; \
            if constexpr (FINAL) {                                            \
                int gyo = y0 + iy - 3, gxo = x0 + ix0 - 3;                    \
                float4 pk;                                                    \
                pk.x = hv0; pk.y = hv1; pk.z = hv2; pk.w = hv3;               \
                *reinterpret_cast<float4*>(outb + (((OC) << 14) + (gyo << 7) + gxo)) = pk; \
            } else {                                                          \
                float* dp = dst + ((OC)*HB + iy)*WB + ix0;                    \
                dp[0] = hv0; dp[1] = hv1; dp[2] = hv2; dp[3] = hv3;           \
            }                                                                 \
        } while (0)
        EPI(0, tA0, tA1, tA2, tA3);
        EPI(1, tB0, tB1, tB2, tB3);
        EPI(2, tC0, tC1, tC2, tC3);
#undef EPI
    }
}

__global__ __launch_bounds__(NT, 8)
void k_main(const float* __restrict__ x,
            const float* __restrict__ ws,
            const float2* __restrict__ tab,
            float* ldacc,
            float* __restrict__ outh)
{
    __shared__ float Sb[2][BUFSZ];
    __shared__ float red[NT/64];
    int t = threadIdx.x;
    int b    = blockIdx.x >> 4;
    int tile = blockIdx.x & 15;
    int y0 = (tile >> 2) << 5, x0 = (tile & 3) << 5;

    // Sb[1] cols 37,38 are read by stage 2's right edge but never written by
    // stage 1 -> zero them (deterministic). 114 rows x 2.
    if (t < 228) Sb[1][(t >> 1)*WB + 37 + (t & 1)] = 0.f;

    const float* xb = x + (size_t)b * 49152;
    // interior 32x32 per channel: coalesced float4, pure shift/mask indexing
    for (int i = t; i < 768; i += NT) {
        int c = i >> 8, r = i & 255, iyr = r >> 3, ixq = (r & 7) << 2;
        float4 v = *reinterpret_cast<const float4*>(xb + c*16384 + ((y0 + iyr) << 7) + x0 + ixq);
        float* dp = &Sb[0][(c*HB + iyr + 3)*WB + 3 + ixq];
        dp[0] = v.x; dp[1] = v.y; dp[2] = v.z; dp[3] = v.w;
    }
    // halo ring: 1260 wrapped elements (rows 0-2/35-37 full, cols 0-2/35-37 sides)
    for (int i = t; i < 1260; i += NT) {
        int c = i / 420; int r = i - c*420;
        int iy, ix;
        if (r < 228) { iy = r / 38; ix = r - iy*38; if (iy >= 3) iy += 32; }
        else { int s2 = r - 228; int row = s2 / 6; int k = s2 - row*6;
               iy = 3 + row; ix = (k < 3) ? k : k + 32; }
        int gy = (y0 + iy - 3) & 127, gx = (x0 + ix - 3) & 127;
        Sb[0][(c*HB + iy)*WB + ix] = xb[c*16384 + (gy << 7) + gx];
    }
    __syncthreads();
    float ldpos = 0.f;
    stage_fn<1, false>(Sb[0], Sb[1], ws, tab, y0, x0, ldpos, nullptr);
    __syncthreads();
    stage_fn<2, false>(Sb[1], Sb[0], ws, tab, y0, x0, ldpos, nullptr);
    __syncthreads();
    stage_fn<3, true >(Sb[0], nullptr, ws, tab, y0, x0, ldpos,
                       outh + (size_t)b * 49152);
    #pragma unroll
    for (int o = 32; o > 0; o >>= 1) ldpos += __shfl_down(ldpos, o, 64);
    if ((t & 63) == 0) red[t >> 6] = ldpos;
    __syncthreads();
    if (t == 0) {
        float s = 0.f;
        #pragma unroll
        for (int wv = 0; wv < NT/64; ++wv) s += red[wv];
        atomicAdd(&ldacc[b], -s);
    }
}

// ---------------- kernel 3: finalize logdet --------------------------------
__global__ void k_fin(const float* __restrict__ ws, float* __restrict__ outld, int B)
{
    int b = blockIdx.x * 256 + threadIdx.x;
    float c = ws[WS_LDC2];
    for (int i = 0; i < 48; ++i) c += ws[WS_LDPART + i];   // uniform -> scalar loads
    if (b < B) outld[b] = c + ws[WS_LDACC + b];
}

extern "C" void kernel_launch(void* const* d_in, const int* in_sizes, int n_in,
                              void* d_out, int out_size, void* d_ws, size_t ws_size,
                              hipStream_t stream)
{
    const float* x   = (const float*)d_in[0];
    const float* ab  = (const float*)d_in[1];
    const float* als = (const float*)d_in[2];
    const float* K   = (const float*)d_in[3];
    const float* cb  = (const float*)d_in[4];
    const float* cls = (const float*)d_in[5];
    const float* la  = (const float*)d_in[6];
    float* ws = (float*)d_ws;
    float* outh = (float*)d_out;                      // fp32: reference output dtype
    float2* tab = (float2*)(ws + WS_TAB);

    const int B = in_sizes[0] / 49152;                // batch from actual input size
    float* outld = outh + (size_t)B * 49152;

    k_pre <<<661,            256, 0, stream>>>(ab, als, K, la, cls, cb, ws, tab, B);
    k_main<<<B * 16,         NT,  0, stream>>>(x, ws, tab, ws + WS_LDACC, outh);
    k_fin <<<(B + 255)/256,  256, 0, stream>>>(ws, outld, B);
}